// Round 4
// baseline (1324.045 us; speedup 1.0000x reference)
//
#include <hip/hip_runtime.h>
#include <hip/hip_bf16.h>
#include <stdint.h>

// Problem constants (B,C,H,W = 2,64,96,96). Inputs fp32, output fp32
// (d_out is float* — the reference output dtype; writing bf16 here was the
// rounds-2/3 failure).
#define BB 2
#define CC 64
#define DD 8
#define PP 9216          // 96*96
#define KT 64            // keys per tile
#define QW 8             // queries per wave
#define TQ 32            // queries per block (4 waves)

__device__ __forceinline__ float readlane_f(float v, int lane) {
    return __uint_as_float(__builtin_amdgcn_readlane(__float_as_uint(v), lane));
}

// ---------------------------------------------------------------------------
// Kernel 1: per-pixel QKV projection.
//   qf[b][p][8] fp32, kf[b][p][8] fp32, vf[b][p][64] bf16
// ---------------------------------------------------------------------------
__global__ __launch_bounds__(256)
void proj_kernel(const float* __restrict__ x,
                 const float* __restrict__ Wq, const float* __restrict__ bq,
                 const float* __restrict__ Wk, const float* __restrict__ bk,
                 const float* __restrict__ Wv, const float* __restrict__ bv,
                 float* __restrict__ qf, float* __restrict__ kf,
                 __hip_bfloat16* __restrict__ vf)
{
    __shared__ float sWq[CC][DD];     // [c][d]
    __shared__ float sWk[CC][DD];
    __shared__ float sWv[CC][CC];     // [c][o]
    __shared__ float sbq[DD], sbk[DD], sbv[CC];

    const int tid = threadIdx.x;

    for (int i = tid; i < DD * CC; i += 256) {
        int d = i / CC, c = i % CC;
        sWq[c][d] = Wq[i];
        sWk[c][d] = Wk[i];
    }
    for (int i = tid; i < CC * CC; i += 256) {
        int o = i / CC, c = i % CC;
        sWv[c][o] = Wv[i];
    }
    if (tid < DD)        sbq[tid] = bq[tid];
    else if (tid < 2*DD) sbk[tid - DD] = bk[tid - DD];
    if (tid >= 2*DD && tid < 2*DD + CC) sbv[tid - 2*DD] = bv[tid - 2*DD];
    __syncthreads();

    const int g = blockIdx.x * 256 + tid;   // global pixel id, 0..18431
    const int b = g / PP;
    const int p = g % PP;

    float qa[DD], ka[DD], va[CC];
#pragma unroll
    for (int d = 0; d < DD; ++d) { qa[d] = 0.f; ka[d] = 0.f; }
#pragma unroll
    for (int o = 0; o < CC; ++o) va[o] = 0.f;

    for (int c = 0; c < CC; ++c) {
        const float xv = x[((size_t)b * CC + c) * PP + p];
#pragma unroll
        for (int d = 0; d < DD; ++d) {
            qa[d] = fmaf(sWq[c][d], xv, qa[d]);
            ka[d] = fmaf(sWk[c][d], xv, ka[d]);
        }
#pragma unroll
        for (int o = 0; o < CC; ++o) {
            va[o] = fmaf(sWv[c][o], xv, va[o]);
        }
    }

    const size_t qb = ((size_t)b * PP + p) * DD;
#pragma unroll
    for (int d = 0; d < DD; ++d) {
        qf[qb + d] = qa[d] + sbq[d];
        kf[qb + d] = ka[d] + sbk[d];
    }
    const size_t vb = ((size_t)b * PP + p) * CC;
#pragma unroll
    for (int o = 0; o < CC; ++o) {
        vf[vb + o] = __float2bfloat16(va[o] + sbv[o]);
    }
}

// ---------------------------------------------------------------------------
// Kernel 2: streaming attention. Block = 256 thr = 4 waves; wave owns QW=8
// queries, lane = output channel. |energy| <~ 3 with the 0.05-scaled
// weights; clamp to +-60 anyway (also scrubs NaN), lsum floored.
// ---------------------------------------------------------------------------
__global__ __launch_bounds__(256)
void attn_kernel(const float* __restrict__ qf, const float* __restrict__ kf,
                 const __hip_bfloat16* __restrict__ vf,
                 const float* __restrict__ x,
                 const float* __restrict__ gamma,
                 float* __restrict__ out)
{
    __shared__ __align__(16) float sv[KT][CC];     // 16 KB, [key][channel]

    const int tid  = threadIdx.x;
    const int lane = tid & 63;
    const int wid  = tid >> 6;

    const int bb = blockIdx.x / (PP / TQ);
    const int i0 = (blockIdx.x % (PP / TQ)) * TQ + wid * QW;  // wave's first query

    // q vectors for the wave's 8 queries (same values in every lane)
    float qreg[QW][DD];
#pragma unroll
    for (int qi = 0; qi < QW; ++qi) {
        const float4* qsrc = (const float4*)(qf + ((size_t)bb * PP + i0 + qi) * DD);
        float4 a = qsrc[0], b4 = qsrc[1];
        qreg[qi][0] = a.x;  qreg[qi][1] = a.y;  qreg[qi][2] = a.z;  qreg[qi][3] = a.w;
        qreg[qi][4] = b4.x; qreg[qi][5] = b4.y; qreg[qi][6] = b4.z; qreg[qi][7] = b4.w;
    }

    float acc[QW], lsum[QW];
#pragma unroll
    for (int qi = 0; qi < QW; ++qi) { acc[qi] = 0.f; lsum[qi] = 0.f; }

    const uint2* vbase = (const uint2*)(vf + (size_t)bb * PP * CC); // 4 bf16 per uint2

    for (int j0 = 0; j0 < PP; j0 += KT) {
        __syncthreads();
        // ---- stage V tile: KT*CC bf16 -> fp32 LDS, fully coalesced ----
#pragma unroll
        for (int i = 0; i < 4; ++i) {
            const int f = tid + i * 256;              // float4 slot in tile (0..1023)
            uint2 u = vbase[(size_t)j0 * (CC / 4) + f];
            float4 fv;
            fv.x = __uint_as_float(u.x << 16);
            fv.y = __uint_as_float(u.x & 0xffff0000u);
            fv.z = __uint_as_float(u.y << 16);
            fv.w = __uint_as_float(u.y & 0xffff0000u);
            ((float4*)&sv[0][0])[f] = fv;
        }
        __syncthreads();

        // ---- energies: this lane handles key j = j0 + lane ----
        const float4* ksrc = (const float4*)(kf + ((size_t)bb * PP + j0 + lane) * DD);
        float4 k0 = ksrc[0], k1 = ksrc[1];
        float kd[DD] = {k0.x, k0.y, k0.z, k0.w, k1.x, k1.y, k1.z, k1.w};

        float w[QW];
#pragma unroll
        for (int qi = 0; qi < QW; ++qi) {
            float e = 0.f;
#pragma unroll
            for (int d = 0; d < DD; ++d) e = fmaf(qreg[qi][d], kd[d], e);
            e = fmaxf(fminf(e, 60.f), -60.f);   // clamp + NaN scrub
            float ww = __expf(e);
            w[qi] = ww;
            lsum[qi] += ww;       // lane's partial over its own keys
        }

        // ---- accumulate: acc[qi] += sum_j w[qi]@lane_j * v[j][lane] ----
#pragma unroll 16
        for (int j = 0; j < KT; ++j) {
            const float vj = sv[j][lane];
#pragma unroll
            for (int qi = 0; qi < QW; ++qi) {
                acc[qi] = fmaf(readlane_f(w[qi], j), vj, acc[qi]);
            }
        }
    }

    // ---- final softmax denominators: reduce lsum across the wave ----
#pragma unroll
    for (int qi = 0; qi < QW; ++qi) {
        float s = lsum[qi];
#pragma unroll
        for (int off = 32; off > 0; off >>= 1) s += __shfl_xor(s, off, 64);
        lsum[qi] = fmaxf(s, 1e-30f);
    }

    const float g = gamma[0];
#pragma unroll
    for (int qi = 0; qi < QW; ++qi) {
        const size_t idx = ((size_t)bb * CC + lane) * PP + (size_t)(i0 + qi);
        const float xv = x[idx];
        out[idx] = fmaf(g, acc[qi] / lsum[qi], xv);   // fp32 store — d_out is float*
    }
}

// ---------------------------------------------------------------------------
extern "C" void kernel_launch(void* const* d_in, const int* in_sizes, int n_in,
                              void* d_out, int out_size, void* d_ws, size_t ws_size,
                              hipStream_t stream)
{
    const float* x     = (const float*)d_in[0];
    const float* Wq    = (const float*)d_in[1];
    const float* bq    = (const float*)d_in[2];
    const float* Wk    = (const float*)d_in[3];
    const float* bk    = (const float*)d_in[4];
    const float* Wv    = (const float*)d_in[5];
    const float* bv    = (const float*)d_in[6];
    const float* gamma = (const float*)d_in[7];
    float* out = (float*)d_out;

    // workspace layout (3.54 MB): qf fp32 | kf fp32 | vf bf16
    float* qf = (float*)d_ws;
    float* kf = qf + (size_t)BB * PP * DD;
    __hip_bfloat16* vf = (__hip_bfloat16*)(kf + (size_t)BB * PP * DD);

    proj_kernel<<<dim3((BB * PP) / 256), dim3(256), 0, stream>>>(
        x, Wq, bq, Wk, bk, Wv, bv, qf, kf, vf);
    attn_kernel<<<dim3((BB * PP) / TQ), dim3(256), 0, stream>>>(
        qf, kf, vf, x, gamma, out);
}

// Round 5
// 202.536 us; speedup vs baseline: 6.5373x; 6.5373x over previous
//
#include <hip/hip_runtime.h>
#include <hip/hip_bf16.h>
#include <stdint.h>

// B,C,H,W = 2,64,96,96. Inputs fp32, output fp32.
// Pipeline: proj2 (QKV 1x1 convs, bf16 outputs) -> attn_mfma (flash-style,
// MFMA QK^T + PV, key-split G=2, fp32 partials) -> combine (normalize,
// transpose, + gamma*attn + x).
#define BB 2
#define CC 64
#define PP 9216
#define GSPLIT 2
#define KEYS_PER_G (PP / GSPLIT)     // 4608
#define QTILES (PP / 64)             // 144

typedef __attribute__((ext_vector_type(8))) short short8;
typedef __attribute__((ext_vector_type(4))) float floatx4;

__device__ __forceinline__ unsigned short f2bf(float f) {
    unsigned int u = __float_as_uint(f);
    u = (u + 0x7fffu + ((u >> 16) & 1u)) >> 16;   // RNE
    return (unsigned short)u;
}

// ---------------------------------------------------------------------------
// Kernel 1: QKV projection. 288 blocks x 256. Thread = (pixel, row-group).
// Rows 0-7: Q, 8-15: K, 16-79: V. Outputs:
//   qb[b][p][8] bf16, kb[b][p][8] bf16, vfw[b][c][p] bf16 (channel-major).
// ---------------------------------------------------------------------------
__global__ __launch_bounds__(256)
void proj2(const float* __restrict__ x,
           const float* __restrict__ Wq, const float* __restrict__ bq,
           const float* __restrict__ Wk, const float* __restrict__ bk,
           const float* __restrict__ Wv, const float* __restrict__ bv,
           unsigned short* __restrict__ qb, unsigned short* __restrict__ kb,
           unsigned short* __restrict__ vfw)
{
    __shared__ float sW[64][80];   // [in-c][row]
    __shared__ float sb[80];

    const int tid = threadIdx.x;
    for (int i = tid; i < 80 * 64; i += 256) {
        const int r = i >> 6, c = i & 63;
        float w = (r < 8) ? Wq[r * 64 + c]
                : (r < 16) ? Wk[(r - 8) * 64 + c]
                : Wv[(r - 16) * 64 + c];
        sW[c][r] = w;
    }
    if (tid < 80) sb[tid] = (tid < 8) ? bq[tid] : (tid < 16) ? bk[tid - 8] : bv[tid - 16];
    __syncthreads();

    const int b  = blockIdx.x / QTILES;
    const int p  = (blockIdx.x % QTILES) * 64 + (tid & 63);
    const int og = tid >> 6;            // wave-uniform row group
    const int r0 = og * 20;

    float acc[20];
#pragma unroll
    for (int r = 0; r < 20; ++r) acc[r] = 0.f;

    for (int c = 0; c < 64; ++c) {
        const float xv = x[((size_t)b * 64 + c) * PP + p];
#pragma unroll
        for (int r = 0; r < 20; ++r) acc[r] = fmaf(sW[c][r0 + r], xv, acc[r]);
    }

#pragma unroll
    for (int r = 0; r < 20; ++r) {
        const int row = r0 + r;
        const unsigned short h = f2bf(acc[r] + sb[row]);
        if (row < 8)       qb[((size_t)b * PP + p) * 8 + row] = h;
        else if (row < 16) kb[((size_t)b * PP + p) * 8 + (row - 8)] = h;
        else               vfw[((size_t)b * 64 + (row - 16)) * PP + p] = h;
    }
}

// ---------------------------------------------------------------------------
// Kernel 2: MFMA flash attention. 576 blocks x 256 (4 waves, 16 q/wave,
// 64 q/block), key range split GSPLIT ways. Per 32-key step:
//   2 MFMA QK^T (d zero-padded 8->32) -> exp (C-layout) -> P via LDS to
//   A-layout -> 4 MFMA PV. Partial acc/lsum (pre-normalization) to ws.
// Layouts (measured, guide S3/m120):
//   C/D: col=lane&15, row=quad*4+reg.  A: A[m=lane&15][k=quad*8+j].
//   B:   B[k=quad*8+j][n=lane&15].
// ---------------------------------------------------------------------------
__global__ __launch_bounds__(256)
void attn_mfma(const unsigned short* __restrict__ qb,
               const unsigned short* __restrict__ kb,
               const unsigned short* __restrict__ vfw,
               float* __restrict__ accp, float* __restrict__ lsump)
{
    __shared__ unsigned short sk[64][40];      // [key][d0..31 padded], rows 80B
    __shared__ unsigned short sv[64][72];      // [ch][key], rows 144B
    __shared__ unsigned short sp[4][16][40];   // per-wave P tile [q][key32]

    const int tid  = threadIdx.x;
    const int lane = tid & 63;
    const int wid  = tid >> 6;
    const int col  = lane & 15;
    const int quad = lane >> 4;

    const int qt = blockIdx.x % QTILES;
    const int gb = blockIdx.x / QTILES;
    const int b  = gb & 1;
    const int g  = gb >> 1;
    const int q0 = qt * 64 + wid * 16;

    // ---- zero-pad region of K tile (d 8..31 stays zero forever) ----
    if (tid < 64) {
        const short8 z = {0,0,0,0,0,0,0,0};
        *(short8*)&sk[tid][8]  = z;
        *(short8*)&sk[tid][16] = z;
        *(short8*)&sk[tid][24] = z;
    }

    // ---- Q fragment: A[m=col][k=d], real d only in quad 0 ----
    short8 qfrag = *(const short8*)(qb + ((size_t)b * PP + q0 + col) * 8);
    if (quad != 0) { const short8 z = {0,0,0,0,0,0,0,0}; qfrag = z; }

    floatx4 acc[4];
#pragma unroll
    for (int cb = 0; cb < 4; ++cb) acc[cb] = (floatx4){0.f, 0.f, 0.f, 0.f};
    float lsum[4] = {0.f, 0.f, 0.f, 0.f};

    const int kbase = g * KEYS_PER_G;
    for (int t = 0; t < KEYS_PER_G / 64; ++t) {
        const int k0 = kbase + t * 64;
        __syncthreads();
        // ---- stage K tile (64 keys x 8 real d) ----
        if (tid < 64) {
            *(short8*)&sk[tid][0] =
                *(const short8*)(kb + ((size_t)b * PP + k0 + tid) * 8);
        }
        // ---- stage V tile transposed-resident: sv[ch][key] ----
        {
            const int ch = tid >> 2, kg = tid & 3;
            const short8* src = (const short8*)(vfw + ((size_t)b * 64 + ch) * PP + k0 + kg * 16);
            *(short8*)&sv[ch][kg * 16]     = src[0];
            *(short8*)&sv[ch][kg * 16 + 8] = src[1];
        }
        __syncthreads();

#pragma unroll
        for (int s = 0; s < 2; ++s) {
            // ---- QK^T: E[q][key16] per half ----
            floatx4 Eh[2];
#pragma unroll
            for (int h = 0; h < 2; ++h) {
                const short8 kf = *(const short8*)&sk[s * 32 + h * 16 + col][quad * 8];
                Eh[h] = __builtin_amdgcn_mfma_f32_16x16x32_bf16(
                    qfrag, kf, (floatx4){0.f, 0.f, 0.f, 0.f}, 0, 0, 0);
            }
            // ---- exp + lsum + P->LDS (C-layout scatter) ----
#pragma unroll
            for (int h = 0; h < 2; ++h) {
#pragma unroll
                for (int r = 0; r < 4; ++r) {
                    float e = Eh[h][r];
                    e = fmaxf(fminf(e, 60.f), -60.f);
                    const float w = __expf(e);
                    lsum[r] += w;
                    sp[wid][quad * 4 + r][h * 16 + col] = f2bf(w);
                }
            }
            __asm__ volatile("s_waitcnt lgkmcnt(0)" ::: "memory");
            // ---- P fragment in A-layout ----
            const short8 pf = *(const short8*)&sp[wid][col][quad * 8];
            // ---- PV: 4 channel blocks ----
#pragma unroll
            for (int cb = 0; cb < 4; ++cb) {
                const short8 vfr = *(const short8*)&sv[cb * 16 + col][s * 32 + quad * 8];
                acc[cb] = __builtin_amdgcn_mfma_f32_16x16x32_bf16(pf, vfr, acc[cb], 0, 0, 0);
            }
        }
    }

    // ---- reduce lsum across the 16 cols (within each quad) ----
#pragma unroll
    for (int r = 0; r < 4; ++r) {
        float s = lsum[r];
        s += __shfl_xor(s, 1, 64);
        s += __shfl_xor(s, 2, 64);
        s += __shfl_xor(s, 4, 64);
        s += __shfl_xor(s, 8, 64);
        lsum[r] = s;
    }

    // ---- store partials ----
    float* ab = accp + (((size_t)g * BB + b) * PP) * 64;
#pragma unroll
    for (int cb = 0; cb < 4; ++cb)
#pragma unroll
        for (int r = 0; r < 4; ++r)
            ab[(size_t)(q0 + quad * 4 + r) * 64 + cb * 16 + col] = acc[cb][r];

    if (col == 0) {
        float4 lv = make_float4(lsum[0], lsum[1], lsum[2], lsum[3]);
        *(float4*)(lsump + ((size_t)g * BB + b) * PP + q0 + quad * 4) = lv;
    }
}

// ---------------------------------------------------------------------------
// Kernel 3: combine partials, normalize, transpose [p][c]->[c][p], + x.
// 288 blocks x 256; block = 64 pixels x 64 channels.
// ---------------------------------------------------------------------------
__global__ __launch_bounds__(256)
void combine(const float* __restrict__ accp, const float* __restrict__ lsump,
             const float* __restrict__ x, const float* __restrict__ gamma,
             float* __restrict__ out)
{
    __shared__ float so[64][68];   // [p][c], rows 272B (16B-aligned)

    const int tid = threadIdx.x;
    const int b   = blockIdx.x / QTILES;
    const int p0  = (blockIdx.x % QTILES) * 64;
    const float gm = gamma[0];

    // phase 1: sum G partials, normalize, stash p-major
    {
        const int p = tid >> 2, cq = tid & 3;
        const size_t r0 = (((size_t)0 * BB + b) * PP + p0 + p) * 64 + cq * 16;
        const size_t r1 = (((size_t)1 * BB + b) * PP + p0 + p) * 64 + cq * 16;
        const float ls = lsump[((size_t)0 * BB + b) * PP + p0 + p]
                       + lsump[((size_t)1 * BB + b) * PP + p0 + p];
        const float inv = gm / fmaxf(ls, 1e-30f);
#pragma unroll
        for (int i = 0; i < 16; i += 4) {
            const float4 a0 = *(const float4*)(accp + r0 + i);
            const float4 a1 = *(const float4*)(accp + r1 + i);
            float4 o;
            o.x = (a0.x + a1.x) * inv;  o.y = (a0.y + a1.y) * inv;
            o.z = (a0.z + a1.z) * inv;  o.w = (a0.w + a1.w) * inv;
            *(float4*)&so[p][cq * 16 + i] = o;
        }
    }
    __syncthreads();
    // phase 2: read transposed, add x, coalesced c-major store
    {
        const int c = tid >> 2, pq = tid & 3;
#pragma unroll
        for (int blk = 0; blk < 4; ++blk) {
            const int pp = pq * 16 + blk * 4;
            const size_t oi = ((size_t)b * 64 + c) * PP + p0 + pp;
            const float4 xv = *(const float4*)(x + oi);
            float4 o;
            o.x = so[pp + 0][c] + xv.x;
            o.y = so[pp + 1][c] + xv.y;
            o.z = so[pp + 2][c] + xv.z;
            o.w = so[pp + 3][c] + xv.w;
            *(float4*)(out + oi) = o;
        }
    }
}

// ---------------------------------------------------------------------------
extern "C" void kernel_launch(void* const* d_in, const int* in_sizes, int n_in,
                              void* d_out, int out_size, void* d_ws, size_t ws_size,
                              hipStream_t stream)
{
    const float* x     = (const float*)d_in[0];
    const float* Wq    = (const float*)d_in[1];
    const float* bq    = (const float*)d_in[2];
    const float* Wk    = (const float*)d_in[3];
    const float* bk    = (const float*)d_in[4];
    const float* Wv    = (const float*)d_in[5];
    const float* bv    = (const float*)d_in[6];
    const float* gamma = (const float*)d_in[7];
    float* out = (float*)d_out;

    // ws layout: qb | kb | vfw (bf16) | accp | lsump (fp32) ~= 12.5 MB
    unsigned short* qb  = (unsigned short*)d_ws;
    unsigned short* kb  = qb + (size_t)BB * PP * 8;
    unsigned short* vfw = kb + (size_t)BB * PP * 8;
    float* accp  = (float*)(vfw + (size_t)BB * CC * PP);
    float* lsump = accp + (size_t)GSPLIT * BB * PP * 64;

    proj2<<<dim3(BB * QTILES), dim3(256), 0, stream>>>(
        x, Wq, bq, Wk, bk, Wv, bv, qb, kb, vfw);
    attn_mfma<<<dim3(GSPLIT * BB * QTILES), dim3(256), 0, stream>>>(
        qb, kb, vfw, accp, lsump);
    combine<<<dim3(BB * QTILES), dim3(256), 0, stream>>>(
        accp, lsump, x, gamma, out);
}

// Round 6
// 155.992 us; speedup vs baseline: 8.4879x; 1.2984x over previous
//
#include <hip/hip_runtime.h>
#include <hip/hip_bf16.h>
#include <stdint.h>

// B,C,H,W = 2,64,96,96. Inputs fp32, output fp32.
// proj2: QKV 1x1 convs -> bf16 q(*log2e),k, V key-permuted channel-major.
// attn2: barrier-free flash attention; K/V frags loaded DIRECT from global
//        (L2-resident), only P round-trips through LDS. Wave = 64q x 32keys.
// combine: sum G key-split partials, normalize, + gamma*attn + x.
#define BB 2
#define CC 64
#define PP 9216
#define QTILES 144               // PP/64
#define LOG2E 1.4426950408889634f

typedef unsigned short ushort;
typedef __attribute__((ext_vector_type(8))) short short8;
typedef __attribute__((ext_vector_type(4))) float floatx4;

#if defined(__has_builtin)
#if __has_builtin(__builtin_amdgcn_exp2f)
#define EXP2(x) __builtin_amdgcn_exp2f(x)
#endif
#endif
#ifndef EXP2
#define EXP2(x) exp2f(x)
#endif

__device__ __forceinline__ ushort f2bf(float f) {
    unsigned int u = __float_as_uint(f);
    u = (u + 0x7fffu + ((u >> 16) & 1u)) >> 16;   // RNE
    return (ushort)u;
}

__device__ __forceinline__ unsigned int pack_bf2(float w0, float w1) {
    // round-half-up bf16 pair, packed with one v_perm_b32
    unsigned int u0 = __float_as_uint(w0) + 0x8000u;
    unsigned int u1 = __float_as_uint(w1) + 0x8000u;
#if defined(__has_builtin) && __has_builtin(__builtin_amdgcn_perm)
    return __builtin_amdgcn_perm(u1, u0, 0x07060302u);
#else
    return (u1 & 0xffff0000u) | (u0 >> 16);
#endif
}

// ---------------------------------------------------------------------------
// Kernel 1: QKV projection. 288 blocks x 512 (8 waves; wave = 64 px x 10 rows).
// Rows 0-7: q (scaled by LOG2E), 8-15: k, 16-79: v (key-permuted in p).
// ---------------------------------------------------------------------------
__global__ __launch_bounds__(512)
void proj2(const float* __restrict__ x,
           const float* __restrict__ Wq, const float* __restrict__ bq,
           const float* __restrict__ Wk, const float* __restrict__ bk,
           const float* __restrict__ Wv, const float* __restrict__ bv,
           ushort* __restrict__ qbuf, ushort* __restrict__ kbuf,
           ushort* __restrict__ vfw)
{
    const int tid = threadIdx.x;
    const int px  = tid & 63;
    const int og  = __builtin_amdgcn_readfirstlane(tid >> 6);  // 0..7, wave-uniform
    const int b   = blockIdx.x / QTILES;
    const int p   = (blockIdx.x % QTILES) * 64 + px;

    // wave-uniform row pointers (rows og*10 .. og*10+9)
    const float* wr[10];
    const int r0 = og * 10;
#pragma unroll
    for (int r = 0; r < 10; ++r) {
        const int row = r0 + r;
        wr[r] = (row < 8) ? (Wq + row * 64)
              : (row < 16) ? (Wk + (row - 8) * 64)
              : (Wv + (row - 16) * 64);
    }

    // x column in registers
    float xv[64];
#pragma unroll
    for (int c = 0; c < 64; ++c)
        xv[c] = x[((size_t)b * 64 + c) * PP + p];

    float acc[10];
#pragma unroll
    for (int r = 0; r < 10; ++r) acc[r] = 0.f;
#pragma unroll
    for (int c = 0; c < 64; ++c) {
#pragma unroll
        for (int r = 0; r < 10; ++r)
            acc[r] = fmaf(wr[r][c], xv[c], acc[r]);
    }

#pragma unroll
    for (int r = 0; r < 10; ++r) {
        const int row = r0 + r;
        if (row < 8) {
            const float v = (acc[r] + bq[row]) * LOG2E;
            qbuf[((size_t)b * PP + p) * 8 + row] = f2bf(v);
        } else if (row < 16) {
            const float v = acc[r] + bk[row - 8];
            kbuf[((size_t)b * PP + p) * 8 + (row - 8)] = f2bf(v);
        } else {
            const int co = row - 16;
            const float v = acc[r] + bv[co];
            const int pl = p & 31;                       // key-permute in 32-group
            const int ps = (p & ~31) | (2 * (pl & 15) + (pl >> 4));
            vfw[((size_t)b * 64 + co) * PP + ps] = f2bf(v);
        }
    }
}

// ---------------------------------------------------------------------------
// Kernel 2: barrier-free MFMA flash attention. Grid = G*BB*QTILES blocks of
// 128 (2 waves). Block = 64 queries; wave wid handles keys [.. + wid*32, +32)
// of each 64-key tile. K/V fragments direct from global; P via per-wave LDS.
// MFMA layouts (measured): C/D col=lane&15,row=quad*4+r; A[m=lane&15][k=q*8+j];
// B[k=quad*8+j][n=lane&15].
// ---------------------------------------------------------------------------
__global__ __launch_bounds__(128)
void attn2(const ushort* __restrict__ qbuf, const ushort* __restrict__ kbuf,
           const ushort* __restrict__ vfw,
           ushort* __restrict__ accp, float* __restrict__ lsump,
           int keysPerG, int numTiles)
{
    __shared__ __align__(16) ushort sp[2][64][36];    // per-wave P tile, 9216 B
    __shared__ __align__(16) float  smerge[64 * 64];  // 16 KB epilogue merge
    __shared__ float slsum[64];

    const int tid  = threadIdx.x;
    const int lane = tid & 63;
    const int wid  = tid >> 6;
    const int col  = lane & 15;
    const int quad = lane >> 4;

    const int qt = blockIdx.x % QTILES;
    const int gb = blockIdx.x / QTILES;
    const int b  = gb % BB;
    const int g  = gb / BB;
    const int q0 = qt * 64;

    const short8 zf = {0, 0, 0, 0, 0, 0, 0, 0};

    // Q fragments (A-layout): real d only in quad 0
    short8 qfrag[4];
#pragma unroll
    for (int qh = 0; qh < 4; ++qh)
        qfrag[qh] = (quad == 0)
            ? *(const short8*)(qbuf + ((size_t)b * PP + q0 + qh * 16 + col) * 8)
            : zf;

    floatx4 acc[4][4];
#pragma unroll
    for (int qh = 0; qh < 4; ++qh)
#pragma unroll
        for (int cb = 0; cb < 4; ++cb) acc[qh][cb] = (floatx4){0.f, 0.f, 0.f, 0.f};
    float lsum[4][4] = {};

    const ushort* kB = kbuf + (size_t)b * PP * 8;
    const ushort* vB = vfw + (size_t)b * 64 * PP;
    const int kwbase = g * keysPerG + wid * 32;

    for (int t = 0; t < numTiles; ++t) {
        const int k0 = kwbase + t * 64;

        // ---- K fragments direct from global (B-operand, d zero-padded) ----
        const short8 kf0 = (quad == 0) ? *(const short8*)(kB + (size_t)(k0 + col) * 8) : zf;
        const short8 kf1 = (quad == 0) ? *(const short8*)(kB + (size_t)(k0 + 16 + col) * 8) : zf;

        // ---- QK^T: E[q][key16] x 2 halves x 4 q-groups ----
        floatx4 E[4][2];
#pragma unroll
        for (int qh = 0; qh < 4; ++qh) {
            E[qh][0] = __builtin_amdgcn_mfma_f32_16x16x32_bf16(
                qfrag[qh], kf0, (floatx4){0.f, 0.f, 0.f, 0.f}, 0, 0, 0);
            E[qh][1] = __builtin_amdgcn_mfma_f32_16x16x32_bf16(
                qfrag[qh], kf1, (floatx4){0.f, 0.f, 0.f, 0.f}, 0, 0, 0);
        }

        // ---- V fragments direct from global (A-operand, keys pre-permuted) ----
        short8 vfr[4];
#pragma unroll
        for (int cb = 0; cb < 4; ++cb)
            vfr[cb] = *(const short8*)(vB + ((size_t)(cb * 16 + col)) * PP + k0 + quad * 8);

        // ---- exp2 + lsum + packed P scatter (keys permuted: pos 2*col+h) ----
#pragma unroll
        for (int qh = 0; qh < 4; ++qh) {
#pragma unroll
            for (int r = 0; r < 4; ++r) {
                const float w0 = EXP2(E[qh][0][r]);
                const float w1 = EXP2(E[qh][1][r]);
                lsum[qh][r] += w0 + w1;
                *(unsigned int*)&sp[wid][qh * 16 + quad * 4 + r][2 * col] = pack_bf2(w0, w1);
            }
        }
        __asm__ volatile("s_waitcnt lgkmcnt(0)" ::: "memory");

        // ---- PV: acc[c][q] += V^T * P^T ----
#pragma unroll
        for (int qh = 0; qh < 4; ++qh) {
            const short8 pf = *(const short8*)&sp[wid][qh * 16 + col][quad * 8];
#pragma unroll
            for (int cb = 0; cb < 4; ++cb)
                acc[qh][cb] = __builtin_amdgcn_mfma_f32_16x16x32_bf16(
                    vfr[cb], pf, acc[qh][cb], 0, 0, 0);
        }
    }

    // ---- reduce lsum across the 16 key-cols ----
#pragma unroll
    for (int qh = 0; qh < 4; ++qh)
#pragma unroll
        for (int r = 0; r < 4; ++r) {
            float s = lsum[qh][r];
            s += __shfl_xor(s, 1, 64);
            s += __shfl_xor(s, 2, 64);
            s += __shfl_xor(s, 4, 64);
            s += __shfl_xor(s, 8, 64);
            lsum[qh][r] = s;
        }

    // ---- merge the two waves' key-halves via LDS; wave 0 stores ----
    if (wid == 1) {
#pragma unroll
        for (int qh = 0; qh < 4; ++qh)
#pragma unroll
            for (int cb = 0; cb < 4; ++cb)
#pragma unroll
                for (int r = 0; r < 4; ++r)
                    smerge[(cb * 16 + quad * 4 + r) * 64 + qh * 16 + col] = acc[qh][cb][r];
        if (col == 0)
#pragma unroll
            for (int qh = 0; qh < 4; ++qh)
#pragma unroll
                for (int r = 0; r < 4; ++r)
                    slsum[qh * 16 + quad * 4 + r] = lsum[qh][r];
    }
    __syncthreads();
    if (wid == 0) {
        ushort* ab = accp + ((size_t)g * BB + b) * CC * PP;
#pragma unroll
        for (int qh = 0; qh < 4; ++qh)
#pragma unroll
            for (int cb = 0; cb < 4; ++cb)
#pragma unroll
                for (int r = 0; r < 4; ++r) {
                    const int c = cb * 16 + quad * 4 + r;
                    const float v = acc[qh][cb][r] + smerge[c * 64 + qh * 16 + col];
                    ab[(size_t)c * PP + q0 + qh * 16 + col] = f2bf(v);
                }
        if (col == 0) {
            float* lb = lsump + ((size_t)g * BB + b) * PP + q0;
#pragma unroll
            for (int qh = 0; qh < 4; ++qh) {
                float4 lv;
                lv.x = lsum[qh][0] + slsum[qh * 16 + quad * 4 + 0];
                lv.y = lsum[qh][1] + slsum[qh * 16 + quad * 4 + 1];
                lv.z = lsum[qh][2] + slsum[qh * 16 + quad * 4 + 2];
                lv.w = lsum[qh][3] + slsum[qh * 16 + quad * 4 + 3];
                *(float4*)(lb + qh * 16 + quad * 4) = lv;
            }
        }
    }
}

// ---------------------------------------------------------------------------
// Kernel 3: combine G partials, normalize, + gamma*attn + x. 576 x 256,
// 8 consecutive pixels per thread (layouts already [b][c][p]-major).
// ---------------------------------------------------------------------------
__global__ __launch_bounds__(256)
void combine(const ushort* __restrict__ accp, const float* __restrict__ lsump,
             const float* __restrict__ x, const float* __restrict__ gamma,
             float* __restrict__ out, int G)
{
    const size_t i8 = ((size_t)blockIdx.x * 256 + threadIdx.x) * 8;
    const int b = (int)(i8 / ((size_t)CC * PP));
    const int p = (int)(i8 % PP);
    const float gm = gamma[0];

    float asum[8] = {}, lst[8] = {};
    for (int g = 0; g < G; ++g) {
        const uint4 av = *(const uint4*)(accp + (size_t)g * (BB * CC * PP) + i8);
        const unsigned int u[4] = {av.x, av.y, av.z, av.w};
#pragma unroll
        for (int k = 0; k < 4; ++k) {
            asum[2 * k]     += __uint_as_float(u[k] << 16);
            asum[2 * k + 1] += __uint_as_float(u[k] & 0xffff0000u);
        }
        const float* lp = lsump + ((size_t)g * BB + b) * PP + p;
        const float4 l0 = *(const float4*)lp;
        const float4 l1 = *(const float4*)(lp + 4);
        lst[0] += l0.x; lst[1] += l0.y; lst[2] += l0.z; lst[3] += l0.w;
        lst[4] += l1.x; lst[5] += l1.y; lst[6] += l1.z; lst[7] += l1.w;
    }

    const float4 x0 = *(const float4*)(x + i8);
    const float4 x1 = *(const float4*)(x + i8 + 4);
    float o[8] = {x0.x, x0.y, x0.z, x0.w, x1.x, x1.y, x1.z, x1.w};
#pragma unroll
    for (int j = 0; j < 8; ++j)
        o[j] = fmaf(asum[j], gm / fmaxf(lst[j], 1e-30f), o[j]);
    *(float4*)(out + i8)     = make_float4(o[0], o[1], o[2], o[3]);
    *(float4*)(out + i8 + 4) = make_float4(o[4], o[5], o[6], o[7]);
}

// ---------------------------------------------------------------------------
extern "C" void kernel_launch(void* const* d_in, const int* in_sizes, int n_in,
                              void* d_out, int out_size, void* d_ws, size_t ws_size,
                              hipStream_t stream)
{
    const float* x     = (const float*)d_in[0];
    const float* Wq    = (const float*)d_in[1];
    const float* bq    = (const float*)d_in[2];
    const float* Wk    = (const float*)d_in[3];
    const float* bk    = (const float*)d_in[4];
    const float* Wv    = (const float*)d_in[5];
    const float* bv    = (const float*)d_in[6];
    const float* gamma = (const float*)d_in[7];
    float* out = (float*)d_out;

    // ws: qbuf | kbuf | vfw (bf16) | accp (bf16, G slots) | lsump (f32)
    const size_t nQK  = (size_t)BB * PP * 8;        // elems
    const size_t nV   = (size_t)BB * CC * PP;
    const size_t base = 2 * nQK * 2 + nV * 2;       // bytes
    const size_t perG = nV * 2 + (size_t)BB * PP * 4;
    const int G = (ws_size >= base + 6 * perG) ? 6
                : (ws_size >= base + 4 * perG) ? 4 : 2;
    const int keysPerG = PP / G;
    const int numTiles = keysPerG / 64;

    ushort* qbuf = (ushort*)d_ws;
    ushort* kbuf = qbuf + nQK;
    ushort* vfw  = kbuf + nQK;
    ushort* accp = vfw + nV;
    float* lsump = (float*)(accp + (size_t)G * nV);

    proj2<<<dim3(BB * QTILES), dim3(512), 0, stream>>>(
        x, Wq, bq, Wk, bk, Wv, bv, qbuf, kbuf, vfw);
    attn2<<<dim3(G * BB * QTILES), dim3(128), 0, stream>>>(
        qbuf, kbuf, vfw, accp, lsump, keysPerG, numTiles);
    combine<<<dim3(576), dim3(256), 0, stream>>>(
        accp, lsump, x, gamma, out, G);
}

// Round 7
// 147.483 us; speedup vs baseline: 8.9776x; 1.0577x over previous
//
#include <hip/hip_runtime.h>
#include <hip/hip_bf16.h>
#include <stdint.h>

// B,C,H,W = 2,64,96,96. Inputs fp32, output fp32.
// proj2: QKV 1x1 convs -> bf16 q(*log2e), k, V key-PERMUTED channel-major.
// attn3: flash attention with ZERO LDS in the K-loop: QK computed as
//        D[key][q] (A=K,B=Q) so P exits in the exact B-operand layout PV
//        needs (keys pre-permuted into slot order in V). P packed in regs.
// combine: sum G key-split partials, normalize, + gamma*attn + x.
#define BB 2
#define CC 64
#define PP 9216
#define QTILES 144               // PP/64
#define LOG2E 1.4426950408889634f

typedef unsigned short ushort;
typedef __attribute__((ext_vector_type(8))) short short8;
typedef __attribute__((ext_vector_type(4))) float floatx4;
typedef __attribute__((ext_vector_type(4))) int intx4;

#if defined(__has_builtin)
#if __has_builtin(__builtin_amdgcn_exp2f)
#define EXP2(x) __builtin_amdgcn_exp2f(x)
#endif
#endif
#ifndef EXP2
#define EXP2(x) exp2f(x)
#endif

__device__ __forceinline__ ushort f2bf(float f) {
    unsigned int u = __float_as_uint(f);
    u = (u + 0x7fffu + ((u >> 16) & 1u)) >> 16;   // RNE
    return (ushort)u;
}

__device__ __forceinline__ unsigned int pack_bf2(float w0, float w1) {
    // bf16 pair (round-half-up), packed with one v_perm_b32
    unsigned int u0 = __float_as_uint(w0) + 0x8000u;
    unsigned int u1 = __float_as_uint(w1) + 0x8000u;
#if defined(__has_builtin) && __has_builtin(__builtin_amdgcn_perm)
    return __builtin_amdgcn_perm(u1, u0, 0x07060302u);
#else
    return (u1 & 0xffff0000u) | (u0 >> 16);
#endif
}

// ---------------------------------------------------------------------------
// Kernel 1: QKV projection. 288 blocks x 512 (8 waves; wave = 64 px x 10 rows).
// Rows 0-7: q (scaled by LOG2E), 8-15: k, 16-79: v.
// V keys permuted within 32-groups: slot = ((k>>2)&3)*8 + ((k>>4)&1)*4 + (k&3)
// so that PV's B-operand slot k'=quad*8+j matches QK's D[key][q] output rows.
// ---------------------------------------------------------------------------
__global__ __launch_bounds__(512)
void proj2(const float* __restrict__ x,
           const float* __restrict__ Wq, const float* __restrict__ bq,
           const float* __restrict__ Wk, const float* __restrict__ bk,
           const float* __restrict__ Wv, const float* __restrict__ bv,
           ushort* __restrict__ qbuf, ushort* __restrict__ kbuf,
           ushort* __restrict__ vfw)
{
    const int tid = threadIdx.x;
    const int px  = tid & 63;
    const int og  = __builtin_amdgcn_readfirstlane(tid >> 6);  // 0..7, wave-uniform
    const int b   = blockIdx.x / QTILES;
    const int p   = (blockIdx.x % QTILES) * 64 + px;

    // wave-uniform row pointers (rows og*10 .. og*10+9)
    const float* wr[10];
    const int r0 = og * 10;
#pragma unroll
    for (int r = 0; r < 10; ++r) {
        const int row = r0 + r;
        wr[r] = (row < 8) ? (Wq + row * 64)
              : (row < 16) ? (Wk + (row - 8) * 64)
              : (Wv + (row - 16) * 64);
    }

    // x column in registers
    float xv[64];
#pragma unroll
    for (int c = 0; c < 64; ++c)
        xv[c] = x[((size_t)b * 64 + c) * PP + p];

    float acc[10];
#pragma unroll
    for (int r = 0; r < 10; ++r) acc[r] = 0.f;
#pragma unroll
    for (int c = 0; c < 64; ++c) {
#pragma unroll
        for (int r = 0; r < 10; ++r)
            acc[r] = fmaf(wr[r][c], xv[c], acc[r]);
    }

#pragma unroll
    for (int r = 0; r < 10; ++r) {
        const int row = r0 + r;
        if (row < 8) {
            const float v = (acc[r] + bq[row]) * LOG2E;
            qbuf[((size_t)b * PP + p) * 8 + row] = f2bf(v);
        } else if (row < 16) {
            const float v = acc[r] + bk[row - 8];
            kbuf[((size_t)b * PP + p) * 8 + (row - 8)] = f2bf(v);
        } else {
            const int co = row - 16;
            const float v = acc[r] + bv[co];
            const int pl = p & 31;     // slot permutation within 32-group
            const int ps = (p & ~31) | ((((pl >> 2) & 3) << 3) | (((pl >> 4) & 1) << 2) | (pl & 3));
            vfw[((size_t)b * 64 + co) * PP + ps] = f2bf(v);
        }
    }
}

// ---------------------------------------------------------------------------
// Kernel 2: zero-LDS-loop MFMA flash attention. Grid = G*BB*QTILES blocks of
// 128 (2 waves; wave = 64 q x 32 keys of each 64-key tile).
// QK: E = mfma(A=K, B=Q) -> D[key=quad*4+r (+16h)][q=col]. K quads 1-3 load
// garbage (harmless: Q's B-frag k-slots >=8 are zeroed). P packed in regs as
// PV's B-operand (V key-permuted to slot order). K frags prefetch-rotated.
// ---------------------------------------------------------------------------
__global__ __launch_bounds__(128)
void attn3(const ushort* __restrict__ qbuf, const ushort* __restrict__ kbuf,
           const ushort* __restrict__ vfw,
           ushort* __restrict__ accp, float* __restrict__ lsump,
           int keysPerG, int numTiles)
{
    __shared__ __align__(16) float smerge[64 * 64];  // 16 KB epilogue merge
    __shared__ float slsum[64];

    const int tid  = threadIdx.x;
    const int lane = tid & 63;
    const int wid  = tid >> 6;
    const int col  = lane & 15;
    const int quad = lane >> 4;

    const int qt = blockIdx.x % QTILES;
    const int gb = blockIdx.x / QTILES;
    const int b  = gb % BB;
    const int g  = gb / BB;
    const int q0 = qt * 64;

    const short8 zf = {0, 0, 0, 0, 0, 0, 0, 0};

    // Q fragments (B-operand: B[k=d=quad*8+j][n=q=col]); only quad 0 real.
    short8 qfragB[4];
#pragma unroll
    for (int qh = 0; qh < 4; ++qh)
        qfragB[qh] = (quad == 0)
            ? *(const short8*)(qbuf + ((size_t)b * PP + q0 + qh * 16 + col) * 8)
            : zf;

    floatx4 acc[4][4];
#pragma unroll
    for (int qh = 0; qh < 4; ++qh)
#pragma unroll
        for (int cb = 0; cb < 4; ++cb) acc[qh][cb] = (floatx4){0.f, 0.f, 0.f, 0.f};
    float lsum[4] = {0.f, 0.f, 0.f, 0.f};

    const ushort* kB = kbuf + (size_t)b * PP * 8;
    const ushort* vB = vfw + (size_t)b * 64 * PP;
    const int kwbase = g * keysPerG + wid * 32;

    // K fragment prefetch (A-operand: A[m=key=col][k=d]; quads 1-3 garbage-ok)
    short8 kf0c = *(const short8*)(kB + (size_t)(kwbase + col) * 8 + quad * 8);
    short8 kf1c = *(const short8*)(kB + (size_t)(kwbase + 16 + col) * 8 + quad * 8);

    for (int t = 0; t < numTiles; ++t) {
        const int kw = kwbase + t * 64;
        const int tn = (t + 1 < numTiles) ? (t + 1) : t;
        const int kwn = kwbase + tn * 64;

        // prefetch next K frags
        const short8 kf0n = *(const short8*)(kB + (size_t)(kwn + col) * 8 + quad * 8);
        const short8 kf1n = *(const short8*)(kB + (size_t)(kwn + 16 + col) * 8 + quad * 8);

        // V fragments (A-operand: A[m=ch=col][k=slot=quad*8+j], keys permuted)
        short8 vfr[4];
#pragma unroll
        for (int cb = 0; cb < 4; ++cb)
            vfr[cb] = *(const short8*)(vB + ((size_t)(cb * 16 + col)) * PP + kw + quad * 8);

        // QK^T: E[key16][q16], 2 key-halves x 4 q-groups
        floatx4 E0[4], E1[4];
#pragma unroll
        for (int qh = 0; qh < 4; ++qh) {
            E0[qh] = __builtin_amdgcn_mfma_f32_16x16x32_bf16(
                kf0c, qfragB[qh], (floatx4){0.f, 0.f, 0.f, 0.f}, 0, 0, 0);
            E1[qh] = __builtin_amdgcn_mfma_f32_16x16x32_bf16(
                kf1c, qfragB[qh], (floatx4){0.f, 0.f, 0.f, 0.f}, 0, 0, 0);
        }

        // exp2 + register P pack + PV
#pragma unroll
        for (int qh = 0; qh < 4; ++qh) {
            const float w00 = EXP2(E0[qh][0]), w01 = EXP2(E0[qh][1]);
            const float w02 = EXP2(E0[qh][2]), w03 = EXP2(E0[qh][3]);
            const float w10 = EXP2(E1[qh][0]), w11 = EXP2(E1[qh][1]);
            const float w12 = EXP2(E1[qh][2]), w13 = EXP2(E1[qh][3]);
            lsum[qh] += ((w00 + w01) + (w02 + w03)) + ((w10 + w11) + (w12 + w13));
            intx4 pi;
            pi.x = pack_bf2(w00, w01);   // slots quad*8 + 0,1
            pi.y = pack_bf2(w02, w03);   // slots quad*8 + 2,3
            pi.z = pack_bf2(w10, w11);   // slots quad*8 + 4,5
            pi.w = pack_bf2(w12, w13);   // slots quad*8 + 6,7
            const short8 pf = __builtin_bit_cast(short8, pi);
#pragma unroll
            for (int cb = 0; cb < 4; ++cb)
                acc[qh][cb] = __builtin_amdgcn_mfma_f32_16x16x32_bf16(
                    vfr[cb], pf, acc[qh][cb], 0, 0, 0);
        }

        kf0c = kf0n;
        kf1c = kf1n;
    }

    // lsum: reduce across the 4 quads (each quad holds 8 of 32 keys per col)
#pragma unroll
    for (int qh = 0; qh < 4; ++qh) {
        float s = lsum[qh];
        s += __shfl_xor(s, 16, 64);
        s += __shfl_xor(s, 32, 64);
        lsum[qh] = s;
    }

    // merge the two waves' key-halves via LDS; wave 0 stores
    if (wid == 1) {
#pragma unroll
        for (int qh = 0; qh < 4; ++qh)
#pragma unroll
            for (int cb = 0; cb < 4; ++cb)
#pragma unroll
                for (int r = 0; r < 4; ++r)
                    smerge[(cb * 16 + quad * 4 + r) * 64 + qh * 16 + col] = acc[qh][cb][r];
        if (quad == 0)
#pragma unroll
            for (int qh = 0; qh < 4; ++qh)
                slsum[qh * 16 + col] = lsum[qh];
    }
    __syncthreads();
    if (wid == 0) {
        ushort* ab = accp + ((size_t)g * BB + b) * CC * PP;
#pragma unroll
        for (int qh = 0; qh < 4; ++qh)
#pragma unroll
            for (int cb = 0; cb < 4; ++cb)
#pragma unroll
                for (int r = 0; r < 4; ++r) {
                    const int c = cb * 16 + quad * 4 + r;
                    const float v = acc[qh][cb][r] + smerge[c * 64 + qh * 16 + col];
                    ab[(size_t)c * PP + q0 + qh * 16 + col] = f2bf(v);
                }
        if (quad == 0) {
            float* lb = lsump + ((size_t)g * BB + b) * PP + q0;
#pragma unroll
            for (int qh = 0; qh < 4; ++qh)
                lb[qh * 16 + col] = lsum[qh] + slsum[qh * 16 + col];
        }
    }
}

// ---------------------------------------------------------------------------
// Kernel 3: combine G partials, normalize, + gamma*attn + x. 576 x 256,
// 8 consecutive pixels per thread (layouts already [b][c][p]-major).
// ---------------------------------------------------------------------------
__global__ __launch_bounds__(256)
void combine(const ushort* __restrict__ accp, const float* __restrict__ lsump,
             const float* __restrict__ x, const float* __restrict__ gamma,
             float* __restrict__ out, int G)
{
    const size_t i8 = ((size_t)blockIdx.x * 256 + threadIdx.x) * 8;
    const int b = (int)(i8 / ((size_t)CC * PP));
    const int p = (int)(i8 % PP);
    const float gm = gamma[0];

    float asum[8] = {}, lst[8] = {};
    for (int g = 0; g < G; ++g) {
        const uint4 av = *(const uint4*)(accp + (size_t)g * (BB * CC * PP) + i8);
        const unsigned int u[4] = {av.x, av.y, av.z, av.w};
#pragma unroll
        for (int k = 0; k < 4; ++k) {
            asum[2 * k]     += __uint_as_float(u[k] << 16);
            asum[2 * k + 1] += __uint_as_float(u[k] & 0xffff0000u);
        }
        const float* lp = lsump + ((size_t)g * BB + b) * PP + p;
        const float4 l0 = *(const float4*)lp;
        const float4 l1 = *(const float4*)(lp + 4);
        lst[0] += l0.x; lst[1] += l0.y; lst[2] += l0.z; lst[3] += l0.w;
        lst[4] += l1.x; lst[5] += l1.y; lst[6] += l1.z; lst[7] += l1.w;
    }

    const float4 x0 = *(const float4*)(x + i8);
    const float4 x1 = *(const float4*)(x + i8 + 4);
    float o[8] = {x0.x, x0.y, x0.z, x0.w, x1.x, x1.y, x1.z, x1.w};
#pragma unroll
    for (int j = 0; j < 8; ++j)
        o[j] = fmaf(asum[j], gm / fmaxf(lst[j], 1e-30f), o[j]);
    *(float4*)(out + i8)     = make_float4(o[0], o[1], o[2], o[3]);
    *(float4*)(out + i8 + 4) = make_float4(o[4], o[5], o[6], o[7]);
}

// ---------------------------------------------------------------------------
extern "C" void kernel_launch(void* const* d_in, const int* in_sizes, int n_in,
                              void* d_out, int out_size, void* d_ws, size_t ws_size,
                              hipStream_t stream)
{
    const float* x     = (const float*)d_in[0];
    const float* Wq    = (const float*)d_in[1];
    const float* bq    = (const float*)d_in[2];
    const float* Wk    = (const float*)d_in[3];
    const float* bk    = (const float*)d_in[4];
    const float* Wv    = (const float*)d_in[5];
    const float* bv    = (const float*)d_in[6];
    const float* gamma = (const float*)d_in[7];
    float* out = (float*)d_out;

    // ws: qbuf | kbuf | vfw (bf16) | accp (bf16, G slots) | lsump (f32)
    const size_t nQK  = (size_t)BB * PP * 8;        // elems
    const size_t nV   = (size_t)BB * CC * PP;
    const size_t base = 2 * nQK * 2 + nV * 2;       // bytes
    const size_t perG = nV * 2 + (size_t)BB * PP * 4;
    const int G = (ws_size >= base + 6 * perG) ? 6
                : (ws_size >= base + 4 * perG) ? 4 : 2;
    const int keysPerG = PP / G;
    const int numTiles = keysPerG / 64;

    ushort* qbuf = (ushort*)d_ws;
    ushort* kbuf = qbuf + nQK;
    ushort* vfw  = kbuf + nQK;
    ushort* accp = vfw + nV;
    float* lsump = (float*)(accp + (size_t)G * nV);

    proj2<<<dim3(BB * QTILES), dim3(512), 0, stream>>>(
        x, Wq, bq, Wk, bk, Wv, bv, qbuf, kbuf, vfw);
    attn3<<<dim3(G * BB * QTILES), dim3(128), 0, stream>>>(
        qbuf, kbuf, vfw, accp, lsump, keysPerG, numTiles);
    combine<<<dim3(576), dim3(256), 0, stream>>>(
        accp, lsump, x, gamma, out, G);
}